// Round 1
// baseline (834.658 us; speedup 1.0000x reference)
//
#include <hip/hip_runtime.h>
#include <math.h>

// WaveNet backbone, fp16-MFMA version, v2: NT=64 -> NT=32.
//  Rationale: grid was 256 blocks = exactly 1 block/CU = 1 wave/SIMD ->
//  every load latency / barrier drain fully exposed (measured ~36 us/layer vs
//  ~4 us roofline). NT=32 doubles the grid to 512 blocks = 2 blocks/CU
//  (launch_bounds(256,2) caps VGPR at 256 so both blocks are resident),
//  giving 2 independent waves/SIMD to overlap stalls.
//  - h chain lives in d_out (outputs[i] is layer i's input); last h -> d_ws.
//  - Per-layer fused kernel: block = 4 waves = 128 c_out x 32 t.
//    Phase 1: x_dil = [W0|W1] @ [h_prv;h_cur]  (K=256 MFMA), fp32 acc kept in regs.
//    Phase 2: tanh/sig convs (K=128) on x_dil (fp16 via LDS), gated epilogue,
//             h_next = x_h + x_dil written fp32.
//    Phase 3: skip conv (K=128) on x_h.
//  - MFMA 16x16x32 f16 layouts (m89/m91/m120-verified):
//      A[m=lane&15][k=(lane>>4)*8+j], B[k=(lane>>4)*8+j][n=lane&15],
//      D[row=(lane>>4)*4+r][col=lane&15].
//  - LDS: sh = B^T tile [t][k=0..255] pitch 264 fp16 (pad 8 -> 2-way banks, free);
//         sx = x_dil fp16 [t][c] pitch 136; sxh aliases sh after phase 1.
//    Total 25.6 KB/block -> LDS allows 6 blocks/CU; VGPR (<=256) allows 2.

typedef _Float16 half8 __attribute__((ext_vector_type(8)));
typedef float floatx4 __attribute__((ext_vector_type(4)));

namespace {
constexpr int C  = 128;
constexpr int S_ = 128;
constexpr int T  = 8192;
constexpr int B_ = 2;
constexpr int L_ = 20;
constexpr int NT = 32;        // time tile per block
constexpr int P1 = 264;       // 256 + 8 fp16 pad (528B rows, 16B aligned)
constexpr int P2 = 136;       // 128 + 8 fp16 pad (272B rows, 16B aligned)
constexpr int DIL[L_] = {1,2,4,8,16,32,64,128,256,512,
                         1,2,4,8,16,32,64,128,256,512};
}

__device__ __forceinline__ float fast_tanh(float x) { return 1.0f - 2.0f / (__expf(2.0f * x) + 1.0f); }
__device__ __forceinline__ float fast_sig (float x) { return 1.0f / (1.0f + __expf(-x)); }

__global__ __launch_bounds__(256) void in_conv(
    const float* __restrict__ x, const float* __restrict__ w_in,
    const float* __restrict__ b_in, float* __restrict__ h0)
{
    int idx = blockIdx.x * 256 + threadIdx.x;   // over B*C*T = 2^21
    int t = idx & (T - 1);
    int c = (idx >> 13) & (C - 1);
    int b = idx >> 20;
    h0[idx] = w_in[c] * x[b * T + t] + b_in[c];
}

__global__ __launch_bounds__(256, 2) void layer_k(
    const float* __restrict__ h_in,  // [B,C,T]
    float* __restrict__ h_out,       // [B,C,T]
    float* __restrict__ skip_out,    // [B,S,T]
    const float* __restrict__ wd, const float* __restrict__ bd,
    const float* __restrict__ wt, const float* __restrict__ bt,
    const float* __restrict__ wsg, const float* __restrict__ bs,
    const float* __restrict__ wk, const float* __restrict__ bk,
    int d)
{
    __shared__ _Float16 sh[NT * P1];   // [t][k]: k<128 = h[t-d][ci], k>=128 = h[t][ci]
    __shared__ _Float16 sx[NT * P2];   // x_dil fp16, [t][c]
    _Float16* sxh = sh;                // x_h fp16, [t][c] — reuses sh after phase 1

    const int tid = threadIdx.x;
    const int b   = blockIdx.y;
    const int t0  = blockIdx.x * NT;
    const float* hb = h_in + (size_t)b * C * T;

    // ---- stage h tiles (global [c][t] -> LDS [t][k], fp16) ----
    for (int f = tid; f < C * (NT / 4); f += 256) {      // current tap -> cols 128+ci
        int ci = f >> 3, tq = f & 7;
        float4 v = *(const float4*)&hb[ci * T + t0 + tq * 4];
        _Float16* p = &sh[(tq * 4) * P1 + 128 + ci];
        p[0] = (_Float16)v.x; p[P1] = (_Float16)v.y;
        p[2 * P1] = (_Float16)v.z; p[3 * P1] = (_Float16)v.w;
    }
    if ((d & 3) == 0) {                                   // dilated tap, aligned float4
        for (int f = tid; f < C * (NT / 4); f += 256) {
            int ci = f >> 3, tq = f & 7;
            int ts = t0 + tq * 4 - d;
            float4 v = make_float4(0.f, 0.f, 0.f, 0.f);
            if (ts >= 0) v = *(const float4*)&hb[ci * T + ts];
            _Float16* p = &sh[(tq * 4) * P1 + ci];
            p[0] = (_Float16)v.x; p[P1] = (_Float16)v.y;
            p[2 * P1] = (_Float16)v.z; p[3 * P1] = (_Float16)v.w;
        }
    } else {                                              // d in {1,2}: scalar guarded
        for (int f = tid; f < C * NT; f += 256) {
            int ci = f >> 5, tt = f & 31;
            int ts = t0 + tt - d;
            sh[tt * P1 + ci] = (ts >= 0) ? (_Float16)hb[ci * T + ts] : (_Float16)0.0f;
        }
    }
    __syncthreads();

    const int lane = tid & 63;
    const int wv   = tid >> 6;      // 0..3
    const int m16  = lane & 15;     // m (A row) / n (B col) / D col
    const int q    = lane >> 4;     // 0..3
    const int cb   = wv * 32;       // wave's c_out base: 2 m-tiles

    // ===== phase 1: x_dil, K=256 =====
    half8 wdf[2][8];
#pragma unroll
    for (int mt = 0; mt < 2; ++mt) {
        const float4* wr = (const float4*)(wd + (size_t)(cb + mt * 16 + m16) * 256);
#pragma unroll
        for (int hf = 0; hf < 4; ++hf) {
            // 16 consecutive floats = w_dil[row][hf*32+q*8 .. +8][0..1] interleaved
            float4 f0 = wr[hf * 16 + q * 4 + 0];
            float4 f1 = wr[hf * 16 + q * 4 + 1];
            float4 f2 = wr[hf * 16 + q * 4 + 2];
            float4 f3 = wr[hf * 16 + q * 4 + 3];
            wdf[mt][hf] = (half8){(_Float16)f0.x, (_Float16)f0.z, (_Float16)f1.x, (_Float16)f1.z,
                                  (_Float16)f2.x, (_Float16)f2.z, (_Float16)f3.x, (_Float16)f3.z};
            wdf[mt][hf + 4] = (half8){(_Float16)f0.y, (_Float16)f0.w, (_Float16)f1.y, (_Float16)f1.w,
                                      (_Float16)f2.y, (_Float16)f2.w, (_Float16)f3.y, (_Float16)f3.w};
        }
    }
    floatx4 bias_d[2];
#pragma unroll
    for (int mt = 0; mt < 2; ++mt)
#pragma unroll
        for (int r = 0; r < 4; ++r) bias_d[mt][r] = bd[cb + mt * 16 + q * 4 + r];

    floatx4 xdacc[2][2];
#pragma unroll
    for (int nt = 0; nt < 2; ++nt) {
        const _Float16* br = &sh[(nt * 16 + m16) * P1 + q * 8];
        half8 bf[8];
#pragma unroll
        for (int kc = 0; kc < 8; ++kc) bf[kc] = *(const half8*)(br + kc * 32);
#pragma unroll
        for (int mt = 0; mt < 2; ++mt) {
            floatx4 acc = bias_d[mt];
#pragma unroll
            for (int kc = 0; kc < 8; ++kc)
                acc = __builtin_amdgcn_mfma_f32_16x16x32_f16(wdf[mt][kc], bf[kc], acc, 0, 0, 0);
            xdacc[mt][nt] = acc;
            _Float16* px = &sx[(nt * 16 + m16) * P2 + cb + mt * 16 + q * 4];
#pragma unroll
            for (int r = 0; r < 4; ++r) px[r] = (_Float16)acc[r];
        }
    }
    __syncthreads();   // sx ready; sh free for reuse as sxh

    // ===== phase 2: tanh/sig convs + gate + residual, K=128 =====
    half8 wtf[2][4], wsf[2][4];
#pragma unroll
    for (int mt = 0; mt < 2; ++mt) {
        const int row = cb + mt * 16 + m16;
#pragma unroll
        for (int kc = 0; kc < 4; ++kc) {
            const float4* p1 = (const float4*)(wt + (size_t)row * 128 + kc * 32 + q * 8);
            float4 a0 = p1[0], a1 = p1[1];
            wtf[mt][kc] = (half8){(_Float16)a0.x, (_Float16)a0.y, (_Float16)a0.z, (_Float16)a0.w,
                                  (_Float16)a1.x, (_Float16)a1.y, (_Float16)a1.z, (_Float16)a1.w};
            const float4* p2 = (const float4*)(wsg + (size_t)row * 128 + kc * 32 + q * 8);
            float4 b0 = p2[0], b1 = p2[1];
            wsf[mt][kc] = (half8){(_Float16)b0.x, (_Float16)b0.y, (_Float16)b0.z, (_Float16)b0.w,
                                  (_Float16)b1.x, (_Float16)b1.y, (_Float16)b1.z, (_Float16)b1.w};
        }
    }
    floatx4 bias_t[2], bias_s[2];
#pragma unroll
    for (int mt = 0; mt < 2; ++mt)
#pragma unroll
        for (int r = 0; r < 4; ++r) {
            bias_t[mt][r] = bt[cb + mt * 16 + q * 4 + r];
            bias_s[mt][r] = bs[cb + mt * 16 + q * 4 + r];
        }

    float* ho = h_out + (size_t)b * C * T;
#pragma unroll
    for (int nt = 0; nt < 2; ++nt) {
        const _Float16* br = &sx[(nt * 16 + m16) * P2 + q * 8];
        half8 bf[4];
#pragma unroll
        for (int kc = 0; kc < 4; ++kc) bf[kc] = *(const half8*)(br + kc * 32);
#pragma unroll
        for (int mt = 0; mt < 2; ++mt) {
            floatx4 at = bias_t[mt], as = bias_s[mt];
#pragma unroll
            for (int kc = 0; kc < 4; ++kc) {
                at = __builtin_amdgcn_mfma_f32_16x16x32_f16(wtf[mt][kc], bf[kc], at, 0, 0, 0);
                as = __builtin_amdgcn_mfma_f32_16x16x32_f16(wsf[mt][kc], bf[kc], as, 0, 0, 0);
            }
            _Float16* pxh = &sxh[(nt * 16 + m16) * P2 + cb + mt * 16 + q * 4];
#pragma unroll
            for (int r = 0; r < 4; ++r) {
                float xh = fast_tanh(at[r]) * fast_sig(as[r]);
                pxh[r] = (_Float16)xh;
                ho[(size_t)(cb + mt * 16 + q * 4 + r) * T + t0 + nt * 16 + m16]
                    = xh + xdacc[mt][nt][r];
            }
        }
    }
    __syncthreads();   // sxh ready

    // ===== phase 3: skip conv, K=128 =====
    half8 wkf[2][4];
#pragma unroll
    for (int mt = 0; mt < 2; ++mt) {
        const int row = cb + mt * 16 + m16;
#pragma unroll
        for (int kc = 0; kc < 4; ++kc) {
            const float4* p1 = (const float4*)(wk + (size_t)row * 128 + kc * 32 + q * 8);
            float4 a0 = p1[0], a1 = p1[1];
            wkf[mt][kc] = (half8){(_Float16)a0.x, (_Float16)a0.y, (_Float16)a0.z, (_Float16)a0.w,
                                  (_Float16)a1.x, (_Float16)a1.y, (_Float16)a1.z, (_Float16)a1.w};
        }
    }
    floatx4 bias_k[2];
#pragma unroll
    for (int mt = 0; mt < 2; ++mt)
#pragma unroll
        for (int r = 0; r < 4; ++r) bias_k[mt][r] = bk[cb + mt * 16 + q * 4 + r];

    float* so = skip_out + (size_t)b * S_ * T;
#pragma unroll
    for (int nt = 0; nt < 2; ++nt) {
        const _Float16* br = &sxh[(nt * 16 + m16) * P2 + q * 8];
        half8 bf[4];
#pragma unroll
        for (int kc = 0; kc < 4; ++kc) bf[kc] = *(const half8*)(br + kc * 32);
#pragma unroll
        for (int mt = 0; mt < 2; ++mt) {
            floatx4 ak = bias_k[mt];
#pragma unroll
            for (int kc = 0; kc < 4; ++kc)
                ak = __builtin_amdgcn_mfma_f32_16x16x32_f16(wkf[mt][kc], bf[kc], ak, 0, 0, 0);
#pragma unroll
            for (int r = 0; r < 4; ++r)
                so[(size_t)(cb + mt * 16 + q * 4 + r) * T + t0 + nt * 16 + m16] = ak[r];
        }
    }
}

extern "C" void kernel_launch(void* const* d_in, const int* in_sizes, int n_in,
                              void* d_out, int out_size, void* d_ws, size_t ws_size,
                              hipStream_t stream)
{
    const float* x      = (const float*)d_in[0];
    const float* w_in   = (const float*)d_in[1];
    const float* b_in   = (const float*)d_in[2];
    const float* w_dil  = (const float*)d_in[3];
    const float* b_dil  = (const float*)d_in[4];
    const float* w_tanh = (const float*)d_in[5];
    const float* b_tanh = (const float*)d_in[6];
    const float* w_sig  = (const float*)d_in[7];
    const float* b_sig  = (const float*)d_in[8];
    const float* w_skip = (const float*)d_in[9];
    const float* b_skip = (const float*)d_in[10];

    float* outs  = (float*)d_out;                        // [L,B,C,T]
    float* skips = outs + (size_t)L_ * B_ * C * T;       // [L,B,S,T]
    float* hlast = (float*)d_ws;                         // discarded final h

    in_conv<<<dim3(B_ * C * T / 256), dim3(256), 0, stream>>>(x, w_in, b_in, outs);

    for (int i = 0; i < L_; ++i) {
        const float* h_in  = outs + (size_t)i * B_ * C * T;
        float* h_out = (i + 1 < L_) ? outs + (size_t)(i + 1) * B_ * C * T : hlast;
        float* sk_o  = skips + (size_t)i * B_ * S_ * T;
        layer_k<<<dim3(T / NT, B_), dim3(256), 0, stream>>>(
            h_in, h_out, sk_o,
            w_dil  + (size_t)i * C * C * 2, b_dil  + (size_t)i * C,
            w_tanh + (size_t)i * C * C,     b_tanh + (size_t)i * C,
            w_sig  + (size_t)i * C * C,     b_sig  + (size_t)i * C,
            w_skip + (size_t)i * S_ * C,    b_skip + (size_t)i * C,
            DIL[i]);
    }
}

// Round 2
// 628.480 us; speedup vs baseline: 1.3281x; 1.3281x over previous
//
#include <hip/hip_runtime.h>
#include <math.h>

// WaveNet backbone, fp16-MFMA, v3: preconverted fp16 weights.
//  v2 post-mortem: NT=32/2-blocks-per-CU REGRESSED (755->835us) => per-block
//  weight fetch+fp32->fp16 convert dominates (80 float4 + ~500 VALU per thread).
//  v3: prep_w kernel converts all layer weights ONCE into d_ws, laid out in
//  exact per-thread MFMA fragment order [kc][q][row][8]; layer_k threads load
//  40 direct 16B half8 fragments (640B/thread, zero convert VALU). NT back to 64.
//  - h chain lives in d_out (outputs[i] is layer i's input); layer 19's h is
//    not stored anywhere (h_out=nullptr) since reference discards it.
//  - Per-layer fused kernel: block = 4 waves = 128 c_out x 64 t.
//    Phase 1: x_dil = [W0|W1] @ [h_prv;h_cur]  (K=256 MFMA), fp32 acc in regs.
//    Phase 2: tanh/sig convs (K=128) on x_dil (fp16 via LDS), gated epilogue,
//             h_next = x_h + x_dil written fp32.
//    Phase 3: skip conv (K=128) on x_h.
//  - MFMA 16x16x32 f16 layouts (m89/m91/m120-verified):
//      A[m=lane&15][k=(lane>>4)*8+j], B[k=(lane>>4)*8+j][n=lane&15],
//      D[row=(lane>>4)*4+r][col=lane&15].
//  - LDS: sh = B^T tile [t][k=0..255] pitch 264 fp16 (pad 8 -> 2-way banks, free);
//         sx = x_dil fp16 [t][c] pitch 136; sxh aliases sh after phase 1.

typedef _Float16 half8 __attribute__((ext_vector_type(8)));
typedef float floatx4 __attribute__((ext_vector_type(4)));
typedef float float4a __attribute__((ext_vector_type(4), aligned(4)));  // dword-aligned ok

namespace {
constexpr int C  = 128;
constexpr int S_ = 128;
constexpr int T  = 8192;
constexpr int B_ = 2;
constexpr int L_ = 20;
constexpr int NT = 64;        // time tile per block
constexpr int P1 = 264;       // 256 + 8 fp16 pad
constexpr int P2 = 136;       // 128 + 8 fp16 pad
constexpr int DIL[L_] = {1,2,4,8,16,32,64,128,256,512,
                         1,2,4,8,16,32,64,128,256,512};
// preconverted weight geometry (units: half8 fragments)
constexpr int WD_FRAG_L = 8 * 4 * 128;        // 4096 frags per layer (w_dil)
constexpr int W1_FRAG_L = 4 * 4 * 128;        // 2048 frags per layer (wt/wsg/wk)
constexpr int NWD = L_ * WD_FRAG_L;           // 81920
constexpr int NW1 = L_ * W1_FRAG_L;           // 40960
}

__device__ __forceinline__ float fast_tanh(float x) { return 1.0f - 2.0f / (__expf(2.0f * x) + 1.0f); }
__device__ __forceinline__ float fast_sig (float x) { return 1.0f / (1.0f + __expf(-x)); }

// Convert fp32 weights -> fp16 fragments, layout [layer][kc][q][row][j=8].
//  wd frag (kc 0..7): tap = kc>>2, ci = (kc&3)*32 + q*8 + j, src wd[l][row][ci][tap]
//  w1 frag (kc 0..3): cin = kc*32 + q*8 + j,                src w [l][row][cin]
__global__ __launch_bounds__(256) void prep_w(
    const float* __restrict__ wd, const float* __restrict__ wt,
    const float* __restrict__ wsg, const float* __restrict__ wk,
    _Float16* __restrict__ out)   // [wd16 | wt16 | wsg16 | wk16]
{
    int fi = blockIdx.x * 256 + threadIdx.x;
    if (fi < NWD) {
        int i  = fi / WD_FRAG_L;
        int r  = fi % WD_FRAG_L;
        int kc = r >> 9;
        int q  = (r >> 7) & 3;
        int row = r & 127;
        int tap = kc >> 2;
        int ci0 = (kc & 3) * 32 + q * 8;
        const float* s = wd + ((size_t)(i * 128 + row) * 128 + ci0) * 2 + tap;
        half8 v;
#pragma unroll
        for (int j = 0; j < 8; ++j) v[j] = (_Float16)s[2 * j];
        *(half8*)(out + (size_t)fi * 8) = v;
        return;
    }
    int fi2 = fi - NWD;
    if (fi2 >= 3 * NW1) return;
    int mtx = fi2 / NW1;                 // 0=wt, 1=wsg, 2=wk
    int r   = fi2 % NW1;
    int i   = r / W1_FRAG_L;
    int rr  = r % W1_FRAG_L;
    int kc  = rr >> 9;
    int q   = (rr >> 7) & 3;
    int row = rr & 127;
    const float* base = (mtx == 0) ? wt : ((mtx == 1) ? wsg : wk);
    const float* s = base + (size_t)(i * 128 + row) * 128 + kc * 32 + q * 8;
    half8 v;
#pragma unroll
    for (int j = 0; j < 8; ++j) v[j] = (_Float16)s[j];
    *(half8*)(out + (size_t)(NWD + fi2) * 8) = v;
}

__global__ __launch_bounds__(256) void in_conv(
    const float* __restrict__ x, const float* __restrict__ w_in,
    const float* __restrict__ b_in, float* __restrict__ h0)
{
    int idx = blockIdx.x * 256 + threadIdx.x;   // over B*C*T = 2^21
    int t = idx & (T - 1);
    int c = (idx >> 13) & (C - 1);
    int b = idx >> 20;
    h0[idx] = w_in[c] * x[b * T + t] + b_in[c];
}

__global__ __launch_bounds__(256, 1) void layer_k(
    const float* __restrict__ h_in,   // [B,C,T]
    float* __restrict__ h_out,        // [B,C,T] or nullptr (last layer)
    float* __restrict__ skip_out,     // [B,S,T]
    const _Float16* __restrict__ wd16, const float* __restrict__ bd,
    const _Float16* __restrict__ wt16, const float* __restrict__ bt,
    const _Float16* __restrict__ ws16, const float* __restrict__ bs,
    const _Float16* __restrict__ wk16, const float* __restrict__ bk,
    int d)
{
    __shared__ _Float16 sh[NT * P1];   // [t][k]: k<128 = h[t-d][ci], k>=128 = h[t][ci]
    __shared__ _Float16 sx[NT * P2];   // x_dil fp16, [t][c]
    _Float16* sxh = sh;                // x_h fp16, [t][c] — reuses sh after phase 1

    const int tid = threadIdx.x;
    const int b   = blockIdx.y;
    const int t0  = blockIdx.x * NT;
    const float* hb = h_in + (size_t)b * C * T;

    // ---- stage h tiles (global [c][t] -> LDS [t][k], fp16) ----
    for (int f = tid; f < C * (NT / 4); f += 256) {      // current tap -> cols 128+ci
        int ci = f >> 4, tq = f & 15;
        float4 v = *(const float4*)&hb[ci * T + t0 + tq * 4];
        _Float16* p = &sh[(tq * 4) * P1 + 128 + ci];
        p[0] = (_Float16)v.x; p[P1] = (_Float16)v.y;
        p[2 * P1] = (_Float16)v.z; p[3 * P1] = (_Float16)v.w;
    }
    for (int f = tid; f < C * (NT / 4); f += 256) {      // dilated tap (any d)
        int ci = f >> 4, tq = f & 15;
        int ts = t0 + tq * 4 - d;
        float4 v;
        if (ts >= 0) {
            float4a u = *(const float4a*)&hb[ci * T + ts];   // dword-aligned load
            v = make_float4(u.x, u.y, u.z, u.w);
        } else {                                              // only first blocks
            v.x = 0.f;
            v.y = (ts + 1 >= 0) ? hb[ci * T + ts + 1] : 0.f;
            v.z = (ts + 2 >= 0) ? hb[ci * T + ts + 2] : 0.f;
            v.w = (ts + 3 >= 0) ? hb[ci * T + ts + 3] : 0.f;
        }
        _Float16* p = &sh[(tq * 4) * P1 + ci];
        p[0] = (_Float16)v.x; p[P1] = (_Float16)v.y;
        p[2 * P1] = (_Float16)v.z; p[3 * P1] = (_Float16)v.w;
    }
    __syncthreads();

    const int lane = tid & 63;
    const int wv   = tid >> 6;      // 0..3
    const int m16  = lane & 15;     // m (A row) / n (B col) / D col
    const int q    = lane >> 4;     // 0..3
    const int cb   = wv * 32;       // wave's c_out base: 2 m-tiles

    // ===== phase 1: x_dil, K=256 =====
    half8 wdf[2][8];
#pragma unroll
    for (int kc = 0; kc < 8; ++kc) {
        const _Float16* p = wd16 + (size_t)((kc * 4 + q) * 128) * 8;
#pragma unroll
        for (int mt = 0; mt < 2; ++mt)
            wdf[mt][kc] = *(const half8*)(p + (cb + mt * 16 + m16) * 8);
    }
    floatx4 bias_d[2];
#pragma unroll
    for (int mt = 0; mt < 2; ++mt)
#pragma unroll
        for (int r = 0; r < 4; ++r) bias_d[mt][r] = bd[cb + mt * 16 + q * 4 + r];

    floatx4 xdacc[2][4];
#pragma unroll
    for (int nt = 0; nt < 4; ++nt) {
        const _Float16* br = &sh[(nt * 16 + m16) * P1 + q * 8];
        half8 bf[8];
#pragma unroll
        for (int kc = 0; kc < 8; ++kc) bf[kc] = *(const half8*)(br + kc * 32);
#pragma unroll
        for (int mt = 0; mt < 2; ++mt) {
            floatx4 acc = bias_d[mt];
#pragma unroll
            for (int kc = 0; kc < 8; ++kc)
                acc = __builtin_amdgcn_mfma_f32_16x16x32_f16(wdf[mt][kc], bf[kc], acc, 0, 0, 0);
            xdacc[mt][nt] = acc;
            _Float16* px = &sx[(nt * 16 + m16) * P2 + cb + mt * 16 + q * 4];
#pragma unroll
            for (int r = 0; r < 4; ++r) px[r] = (_Float16)acc[r];
        }
    }
    __syncthreads();   // sx ready; sh free for reuse as sxh

    // ===== phase 2: tanh/sig convs + gate + residual, K=128 =====
    half8 wtf[2][4], wsf[2][4];
#pragma unroll
    for (int kc = 0; kc < 4; ++kc) {
        const size_t off = (size_t)((kc * 4 + q) * 128) * 8;
#pragma unroll
        for (int mt = 0; mt < 2; ++mt) {
            const int row = cb + mt * 16 + m16;
            wtf[mt][kc] = *(const half8*)(wt16 + off + row * 8);
            wsf[mt][kc] = *(const half8*)(ws16 + off + row * 8);
        }
    }
    floatx4 bias_t[2], bias_s[2];
#pragma unroll
    for (int mt = 0; mt < 2; ++mt)
#pragma unroll
        for (int r = 0; r < 4; ++r) {
            bias_t[mt][r] = bt[cb + mt * 16 + q * 4 + r];
            bias_s[mt][r] = bs[cb + mt * 16 + q * 4 + r];
        }

    float* ho = h_out ? h_out + (size_t)b * C * T : nullptr;
#pragma unroll
    for (int nt = 0; nt < 4; ++nt) {
        const _Float16* br = &sx[(nt * 16 + m16) * P2 + q * 8];
        half8 bf[4];
#pragma unroll
        for (int kc = 0; kc < 4; ++kc) bf[kc] = *(const half8*)(br + kc * 32);
#pragma unroll
        for (int mt = 0; mt < 2; ++mt) {
            floatx4 at = bias_t[mt], as = bias_s[mt];
#pragma unroll
            for (int kc = 0; kc < 4; ++kc) {
                at = __builtin_amdgcn_mfma_f32_16x16x32_f16(wtf[mt][kc], bf[kc], at, 0, 0, 0);
                as = __builtin_amdgcn_mfma_f32_16x16x32_f16(wsf[mt][kc], bf[kc], as, 0, 0, 0);
            }
            _Float16* pxh = &sxh[(nt * 16 + m16) * P2 + cb + mt * 16 + q * 4];
#pragma unroll
            for (int r = 0; r < 4; ++r) {
                float xh = fast_tanh(at[r]) * fast_sig(as[r]);
                pxh[r] = (_Float16)xh;
                if (ho)
                    ho[(size_t)(cb + mt * 16 + q * 4 + r) * T + t0 + nt * 16 + m16]
                        = xh + xdacc[mt][nt][r];
            }
        }
    }
    __syncthreads();   // sxh ready

    // ===== phase 3: skip conv, K=128 =====
    half8 wkf[2][4];
#pragma unroll
    for (int kc = 0; kc < 4; ++kc) {
        const size_t off = (size_t)((kc * 4 + q) * 128) * 8;
#pragma unroll
        for (int mt = 0; mt < 2; ++mt)
            wkf[mt][kc] = *(const half8*)(wk16 + off + (cb + mt * 16 + m16) * 8);
    }
    floatx4 bias_k[2];
#pragma unroll
    for (int mt = 0; mt < 2; ++mt)
#pragma unroll
        for (int r = 0; r < 4; ++r) bias_k[mt][r] = bk[cb + mt * 16 + q * 4 + r];

    float* so = skip_out + (size_t)b * S_ * T;
#pragma unroll
    for (int nt = 0; nt < 4; ++nt) {
        const _Float16* br = &sxh[(nt * 16 + m16) * P2 + q * 8];
        half8 bf[4];
#pragma unroll
        for (int kc = 0; kc < 4; ++kc) bf[kc] = *(const half8*)(br + kc * 32);
#pragma unroll
        for (int mt = 0; mt < 2; ++mt) {
            floatx4 ak = bias_k[mt];
#pragma unroll
            for (int kc = 0; kc < 4; ++kc)
                ak = __builtin_amdgcn_mfma_f32_16x16x32_f16(wkf[mt][kc], bf[kc], ak, 0, 0, 0);
#pragma unroll
            for (int r = 0; r < 4; ++r)
                so[(size_t)(cb + mt * 16 + q * 4 + r) * T + t0 + nt * 16 + m16] = ak[r];
        }
    }
}

extern "C" void kernel_launch(void* const* d_in, const int* in_sizes, int n_in,
                              void* d_out, int out_size, void* d_ws, size_t ws_size,
                              hipStream_t stream)
{
    const float* x      = (const float*)d_in[0];
    const float* w_in   = (const float*)d_in[1];
    const float* b_in   = (const float*)d_in[2];
    const float* w_dil  = (const float*)d_in[3];
    const float* b_dil  = (const float*)d_in[4];
    const float* w_tanh = (const float*)d_in[5];
    const float* b_tanh = (const float*)d_in[6];
    const float* w_sig  = (const float*)d_in[7];
    const float* b_sig  = (const float*)d_in[8];
    const float* w_skip = (const float*)d_in[9];
    const float* b_skip = (const float*)d_in[10];

    float* outs  = (float*)d_out;                        // [L,B,C,T]
    float* skips = outs + (size_t)L_ * B_ * C * T;       // [L,B,S,T]

    // d_ws: preconverted fp16 weights, 3.28 MB total
    _Float16* w16   = (_Float16*)d_ws;
    _Float16* wd16  = w16;                                       // [L][4096]*8
    _Float16* wt16  = w16 + (size_t)NWD * 8;                     // [L][2048]*8
    _Float16* wsg16 = wt16 + (size_t)NW1 * 8;
    _Float16* wk16  = wsg16 + (size_t)NW1 * 8;

    const int total_frags = NWD + 3 * NW1;                       // 204800
    prep_w<<<dim3((total_frags + 255) / 256), dim3(256), 0, stream>>>(
        w_dil, w_tanh, w_sig, w_skip, w16);

    in_conv<<<dim3(B_ * C * T / 256), dim3(256), 0, stream>>>(x, w_in, b_in, outs);

    for (int i = 0; i < L_; ++i) {
        const float* h_in  = outs + (size_t)i * B_ * C * T;
        float* h_out = (i + 1 < L_) ? outs + (size_t)(i + 1) * B_ * C * T : nullptr;
        float* sk_o  = skips + (size_t)i * B_ * S_ * T;
        layer_k<<<dim3(T / NT, B_), dim3(256), 0, stream>>>(
            h_in, h_out, sk_o,
            wd16  + (size_t)i * WD_FRAG_L * 8, b_dil  + (size_t)i * C,
            wt16  + (size_t)i * W1_FRAG_L * 8, b_tanh + (size_t)i * C,
            wsg16 + (size_t)i * W1_FRAG_L * 8, b_sig  + (size_t)i * C,
            wk16  + (size_t)i * W1_FRAG_L * 8, b_skip + (size_t)i * C,
            DIL[i]);
    }
}

// Round 3
// 572.415 us; speedup vs baseline: 1.4581x; 1.0979x over previous
//
#include <hip/hip_runtime.h>
#include <math.h>

// WaveNet backbone, fp16-MFMA, v4: 8-wave blocks for 2 waves/SIMD.
//  v3 post-mortem: preconverted fp16 weights WON (755->628us) => weight path
//  was dominant. Remaining ~30us/layer vs ~2us throughput estimate => kernel
//  is latency-bound at 1 wave/SIMD (grid 256 = 1 block/CU, 4 waves).
//  v4: block = 512 threads = 8 waves (2 t-halves x 4 c-waves), NT=64, grid
//  unchanged at 256 blocks => 1 block/CU but 2 waves/SIMD. Per-thread work
//  halves (nt loop 4->2); weight frags loaded by both t-half waves (2x L2
//  traffic, ~+1.2us/layer — cheap now that frags are direct half8 loads).
//  - h chain lives in d_out (outputs[i] is layer i's input); layer 19's h
//    is discarded (h_out=nullptr).
//  - Phases: 1) x_dil = [W0|W1] @ [h_prv;h_cur] (K=256 MFMA), fp32 acc regs.
//            2) tanh/sig convs (K=128) on x_dil fp16, gated epilogue,
//               h_next = x_h + x_dil written fp32.
//            3) skip conv (K=128) on x_h.
//  - MFMA 16x16x32 f16 layouts (m89/m91/m120-verified):
//      A[m=lane&15][k=(lane>>4)*8+j], B[k=(lane>>4)*8+j][n=lane&15],
//      D[row=(lane>>4)*4+r][col=lane&15].
//  - LDS: sh = B^T tile [t][k=0..255] pitch 264 fp16 (pad 8 -> 2-way, free);
//         sx = x_dil fp16 [t][c] pitch 136; sxh aliases sh after phase 1.

typedef _Float16 half8 __attribute__((ext_vector_type(8)));
typedef float floatx4 __attribute__((ext_vector_type(4)));
typedef float float4a __attribute__((ext_vector_type(4), aligned(4)));  // dword-aligned ok

namespace {
constexpr int C  = 128;
constexpr int S_ = 128;
constexpr int T  = 8192;
constexpr int B_ = 2;
constexpr int L_ = 20;
constexpr int NT = 64;        // time tile per block
constexpr int NTH = 512;      // threads per block (8 waves)
constexpr int P1 = 264;       // 256 + 8 fp16 pad
constexpr int P2 = 136;       // 128 + 8 fp16 pad
constexpr int DIL[L_] = {1,2,4,8,16,32,64,128,256,512,
                         1,2,4,8,16,32,64,128,256,512};
// preconverted weight geometry (units: half8 fragments)
constexpr int WD_FRAG_L = 8 * 4 * 128;        // 4096 frags per layer (w_dil)
constexpr int W1_FRAG_L = 4 * 4 * 128;        // 2048 frags per layer (wt/wsg/wk)
constexpr int NWD = L_ * WD_FRAG_L;           // 81920
constexpr int NW1 = L_ * W1_FRAG_L;           // 40960
}

__device__ __forceinline__ float fast_tanh(float x) { return 1.0f - 2.0f / (__expf(2.0f * x) + 1.0f); }
__device__ __forceinline__ float fast_sig (float x) { return 1.0f / (1.0f + __expf(-x)); }

// Convert fp32 weights -> fp16 fragments, layout [layer][kc][q][row][j=8].
//  wd frag (kc 0..7): tap = kc>>2, ci = (kc&3)*32 + q*8 + j, src wd[l][row][ci][tap]
//  w1 frag (kc 0..3): cin = kc*32 + q*8 + j,                src w [l][row][cin]
__global__ __launch_bounds__(256) void prep_w(
    const float* __restrict__ wd, const float* __restrict__ wt,
    const float* __restrict__ wsg, const float* __restrict__ wk,
    _Float16* __restrict__ out)   // [wd16 | wt16 | wsg16 | wk16]
{
    int fi = blockIdx.x * 256 + threadIdx.x;
    if (fi < NWD) {
        int i  = fi / WD_FRAG_L;
        int r  = fi % WD_FRAG_L;
        int kc = r >> 9;
        int q  = (r >> 7) & 3;
        int row = r & 127;
        int tap = kc >> 2;
        int ci0 = (kc & 3) * 32 + q * 8;
        const float* s = wd + ((size_t)(i * 128 + row) * 128 + ci0) * 2 + tap;
        half8 v;
#pragma unroll
        for (int j = 0; j < 8; ++j) v[j] = (_Float16)s[2 * j];
        *(half8*)(out + (size_t)fi * 8) = v;
        return;
    }
    int fi2 = fi - NWD;
    if (fi2 >= 3 * NW1) return;
    int mtx = fi2 / NW1;                 // 0=wt, 1=wsg, 2=wk
    int r   = fi2 % NW1;
    int i   = r / W1_FRAG_L;
    int rr  = r % W1_FRAG_L;
    int kc  = rr >> 9;
    int q   = (rr >> 7) & 3;
    int row = rr & 127;
    const float* base = (mtx == 0) ? wt : ((mtx == 1) ? wsg : wk);
    const float* s = base + (size_t)(i * 128 + row) * 128 + kc * 32 + q * 8;
    half8 v;
#pragma unroll
    for (int j = 0; j < 8; ++j) v[j] = (_Float16)s[j];
    *(half8*)(out + (size_t)(NWD + fi2) * 8) = v;
}

__global__ __launch_bounds__(256) void in_conv(
    const float* __restrict__ x, const float* __restrict__ w_in,
    const float* __restrict__ b_in, float* __restrict__ h0)
{
    int idx = blockIdx.x * 256 + threadIdx.x;   // over B*C*T = 2^21
    int t = idx & (T - 1);
    int c = (idx >> 13) & (C - 1);
    int b = idx >> 20;
    h0[idx] = w_in[c] * x[b * T + t] + b_in[c];
}

__global__ __launch_bounds__(NTH, 2) void layer_k(
    const float* __restrict__ h_in,   // [B,C,T]
    float* __restrict__ h_out,        // [B,C,T] or nullptr (last layer)
    float* __restrict__ skip_out,     // [B,S,T]
    const _Float16* __restrict__ wd16, const float* __restrict__ bd,
    const _Float16* __restrict__ wt16, const float* __restrict__ bt,
    const _Float16* __restrict__ ws16, const float* __restrict__ bs,
    const _Float16* __restrict__ wk16, const float* __restrict__ bk,
    int d)
{
    __shared__ _Float16 sh[NT * P1];   // [t][k]: k<128 = h[t-d][ci], k>=128 = h[t][ci]
    __shared__ _Float16 sx[NT * P2];   // x_dil fp16, [t][c]
    _Float16* sxh = sh;                // x_h fp16, [t][c] — reuses sh after phase 1

    const int tid = threadIdx.x;
    const int b   = blockIdx.y;
    const int t0  = blockIdx.x * NT;
    const float* hb = h_in + (size_t)b * C * T;

    // ---- stage h tiles (global [c][t] -> LDS [t][k], fp16) ----
    for (int f = tid; f < C * (NT / 4); f += NTH) {      // current tap -> cols 128+ci
        int ci = f >> 4, tq = f & 15;
        float4 v = *(const float4*)&hb[ci * T + t0 + tq * 4];
        _Float16* p = &sh[(tq * 4) * P1 + 128 + ci];
        p[0] = (_Float16)v.x; p[P1] = (_Float16)v.y;
        p[2 * P1] = (_Float16)v.z; p[3 * P1] = (_Float16)v.w;
    }
    for (int f = tid; f < C * (NT / 4); f += NTH) {      // dilated tap (any d)
        int ci = f >> 4, tq = f & 15;
        int ts = t0 + tq * 4 - d;
        float4 v;
        if (ts >= 0) {
            float4a u = *(const float4a*)&hb[ci * T + ts];   // dword-aligned load
            v = make_float4(u.x, u.y, u.z, u.w);
        } else {                                              // only first blocks
            v.x = 0.f;
            v.y = (ts + 1 >= 0) ? hb[ci * T + ts + 1] : 0.f;
            v.z = (ts + 2 >= 0) ? hb[ci * T + ts + 2] : 0.f;
            v.w = (ts + 3 >= 0) ? hb[ci * T + ts + 3] : 0.f;
        }
        _Float16* p = &sh[(tq * 4) * P1 + ci];
        p[0] = (_Float16)v.x; p[P1] = (_Float16)v.y;
        p[2 * P1] = (_Float16)v.z; p[3 * P1] = (_Float16)v.w;
    }
    __syncthreads();

    const int lane = tid & 63;
    const int wv   = tid >> 6;      // 0..7
    const int wc   = wv & 3;        // c-wave: c_out base
    const int th   = wv >> 2;       // t-half: 0 or 1
    const int m16  = lane & 15;     // m (A row) / n (B col) / D col
    const int q    = lane >> 4;     // 0..3
    const int cb   = wc * 32;       // wave's c_out base: 2 m-tiles
    const int tw   = th * 32;       // wave's t base within tile

    // ===== phase 1: x_dil, K=256 =====
    half8 wdf[2][8];
#pragma unroll
    for (int kc = 0; kc < 8; ++kc) {
        const _Float16* p = wd16 + (size_t)((kc * 4 + q) * 128) * 8;
#pragma unroll
        for (int mt = 0; mt < 2; ++mt)
            wdf[mt][kc] = *(const half8*)(p + (cb + mt * 16 + m16) * 8);
    }
    floatx4 bias_d[2];
#pragma unroll
    for (int mt = 0; mt < 2; ++mt)
#pragma unroll
        for (int r = 0; r < 4; ++r) bias_d[mt][r] = bd[cb + mt * 16 + q * 4 + r];

    floatx4 xdacc[2][2];
#pragma unroll
    for (int nt = 0; nt < 2; ++nt) {
        const int rt = tw + nt * 16 + m16;          // time-row within tile
        const _Float16* br = &sh[rt * P1 + q * 8];
        half8 bf[8];
#pragma unroll
        for (int kc = 0; kc < 8; ++kc) bf[kc] = *(const half8*)(br + kc * 32);
#pragma unroll
        for (int mt = 0; mt < 2; ++mt) {
            floatx4 acc = bias_d[mt];
#pragma unroll
            for (int kc = 0; kc < 8; ++kc)
                acc = __builtin_amdgcn_mfma_f32_16x16x32_f16(wdf[mt][kc], bf[kc], acc, 0, 0, 0);
            xdacc[mt][nt] = acc;
            _Float16* px = &sx[rt * P2 + cb + mt * 16 + q * 4];
#pragma unroll
            for (int r = 0; r < 4; ++r) px[r] = (_Float16)acc[r];
        }
    }
    __syncthreads();   // sx ready; sh free for reuse as sxh

    // ===== phase 2: tanh/sig convs + gate + residual, K=128 =====
    half8 wtf[2][4], wsf[2][4];
#pragma unroll
    for (int kc = 0; kc < 4; ++kc) {
        const size_t off = (size_t)((kc * 4 + q) * 128) * 8;
#pragma unroll
        for (int mt = 0; mt < 2; ++mt) {
            const int row = cb + mt * 16 + m16;
            wtf[mt][kc] = *(const half8*)(wt16 + off + row * 8);
            wsf[mt][kc] = *(const half8*)(ws16 + off + row * 8);
        }
    }
    floatx4 bias_t[2], bias_s[2];
#pragma unroll
    for (int mt = 0; mt < 2; ++mt)
#pragma unroll
        for (int r = 0; r < 4; ++r) {
            bias_t[mt][r] = bt[cb + mt * 16 + q * 4 + r];
            bias_s[mt][r] = bs[cb + mt * 16 + q * 4 + r];
        }

    float* ho = h_out ? h_out + (size_t)b * C * T : nullptr;
#pragma unroll
    for (int nt = 0; nt < 2; ++nt) {
        const int rt = tw + nt * 16 + m16;
        const _Float16* br = &sx[rt * P2 + q * 8];
        half8 bf[4];
#pragma unroll
        for (int kc = 0; kc < 4; ++kc) bf[kc] = *(const half8*)(br + kc * 32);
#pragma unroll
        for (int mt = 0; mt < 2; ++mt) {
            floatx4 at = bias_t[mt], as = bias_s[mt];
#pragma unroll
            for (int kc = 0; kc < 4; ++kc) {
                at = __builtin_amdgcn_mfma_f32_16x16x32_f16(wtf[mt][kc], bf[kc], at, 0, 0, 0);
                as = __builtin_amdgcn_mfma_f32_16x16x32_f16(wsf[mt][kc], bf[kc], as, 0, 0, 0);
            }
            _Float16* pxh = &sxh[rt * P2 + cb + mt * 16 + q * 4];
#pragma unroll
            for (int r = 0; r < 4; ++r) {
                float xh = fast_tanh(at[r]) * fast_sig(as[r]);
                pxh[r] = (_Float16)xh;
                if (ho)
                    ho[(size_t)(cb + mt * 16 + q * 4 + r) * T + t0 + rt]
                        = xh + xdacc[mt][nt][r];
            }
        }
    }
    __syncthreads();   // sxh ready

    // ===== phase 3: skip conv, K=128 =====
    half8 wkf[2][4];
#pragma unroll
    for (int kc = 0; kc < 4; ++kc) {
        const size_t off = (size_t)((kc * 4 + q) * 128) * 8;
#pragma unroll
        for (int mt = 0; mt < 2; ++mt)
            wkf[mt][kc] = *(const half8*)(wk16 + off + (cb + mt * 16 + m16) * 8);
    }
    floatx4 bias_k[2];
#pragma unroll
    for (int mt = 0; mt < 2; ++mt)
#pragma unroll
        for (int r = 0; r < 4; ++r) bias_k[mt][r] = bk[cb + mt * 16 + q * 4 + r];

    float* so = skip_out + (size_t)b * S_ * T;
#pragma unroll
    for (int nt = 0; nt < 2; ++nt) {
        const int rt = tw + nt * 16 + m16;
        const _Float16* br = &sxh[rt * P2 + q * 8];
        half8 bf[4];
#pragma unroll
        for (int kc = 0; kc < 4; ++kc) bf[kc] = *(const half8*)(br + kc * 32);
#pragma unroll
        for (int mt = 0; mt < 2; ++mt) {
            floatx4 ak = bias_k[mt];
#pragma unroll
            for (int kc = 0; kc < 4; ++kc)
                ak = __builtin_amdgcn_mfma_f32_16x16x32_f16(wkf[mt][kc], bf[kc], ak, 0, 0, 0);
#pragma unroll
            for (int r = 0; r < 4; ++r)
                so[(size_t)(cb + mt * 16 + q * 4 + r) * T + t0 + rt] = ak[r];
        }
    }
}

extern "C" void kernel_launch(void* const* d_in, const int* in_sizes, int n_in,
                              void* d_out, int out_size, void* d_ws, size_t ws_size,
                              hipStream_t stream)
{
    const float* x      = (const float*)d_in[0];
    const float* w_in   = (const float*)d_in[1];
    const float* b_in   = (const float*)d_in[2];
    const float* w_dil  = (const float*)d_in[3];
    const float* b_dil  = (const float*)d_in[4];
    const float* w_tanh = (const float*)d_in[5];
    const float* b_tanh = (const float*)d_in[6];
    const float* w_sig  = (const float*)d_in[7];
    const float* b_sig  = (const float*)d_in[8];
    const float* w_skip = (const float*)d_in[9];
    const float* b_skip = (const float*)d_in[10];

    float* outs  = (float*)d_out;                        // [L,B,C,T]
    float* skips = outs + (size_t)L_ * B_ * C * T;       // [L,B,S,T]

    // d_ws: preconverted fp16 weights, 3.28 MB total
    _Float16* w16   = (_Float16*)d_ws;
    _Float16* wd16  = w16;                                       // [L][4096]*8
    _Float16* wt16  = w16 + (size_t)NWD * 8;                     // [L][2048]*8
    _Float16* wsg16 = wt16 + (size_t)NW1 * 8;
    _Float16* wk16  = wsg16 + (size_t)NW1 * 8;

    const int total_frags = NWD + 3 * NW1;                       // 204800
    prep_w<<<dim3((total_frags + 255) / 256), dim3(256), 0, stream>>>(
        w_dil, w_tanh, w_sig, w_skip, w16);

    in_conv<<<dim3(B_ * C * T / 256), dim3(256), 0, stream>>>(x, w_in, b_in, outs);

    for (int i = 0; i < L_; ++i) {
        const float* h_in  = outs + (size_t)i * B_ * C * T;
        float* h_out = (i + 1 < L_) ? outs + (size_t)(i + 1) * B_ * C * T : nullptr;
        float* sk_o  = skips + (size_t)i * B_ * S_ * T;
        layer_k<<<dim3(T / NT, B_), dim3(NTH), 0, stream>>>(
            h_in, h_out, sk_o,
            wd16  + (size_t)i * WD_FRAG_L * 8, b_dil  + (size_t)i * C,
            wt16  + (size_t)i * W1_FRAG_L * 8, b_tanh + (size_t)i * C,
            wsg16 + (size_t)i * W1_FRAG_L * 8, b_sig  + (size_t)i * C,
            wk16  + (size_t)i * W1_FRAG_L * 8, b_skip + (size_t)i * C,
            DIL[i]);
    }
}

// Round 4
// 542.626 us; speedup vs baseline: 1.5382x; 1.0549x over previous
//
#include <hip/hip_runtime.h>
#include <math.h>

// WaveNet backbone, fp16-MFMA, v5: 4 waves/SIMD via 2 independent blocks/CU.
//  v4 post-mortem: 8-wave single block/CU gave -9.7% (628->572) — partial;
//  same-block waves share barriers so TLP gain was capped. v5: NT=32, grid
//  512 blocks x 512 thr = 2 blocks/CU, 16 waves/CU, 4 waves/SIMD with
//  INDEPENDENT barriers. To fit launch_bounds(512,4)'s 128-VGPR cap, each
//  wave now owns ONE 16-row c_out slice (8 waves x 16 = 128): wdf 64->32
//  VGPR, and the block's 8 waves cover the weight set exactly once
//  (160KB/block, no duplication).
//  - h chain lives in d_out (outputs[i] is layer i's input); layer 19's h
//    is discarded (h_out=nullptr).
//  - Phases: 1) x_dil = [W0|W1] @ [h_prv;h_cur] (K=256 MFMA), fp32 acc regs.
//            2) tanh/sig convs (K=128) on x_dil fp16, gated epilogue,
//               h_next = x_h + x_dil written fp32.
//            3) skip conv (K=128) on x_h.
//  - MFMA 16x16x32 f16 layouts (m89/m91/m120-verified):
//      A[m=lane&15][k=(lane>>4)*8+j], B[k=(lane>>4)*8+j][n=lane&15],
//      D[row=(lane>>4)*4+r][col=lane&15].
//  - LDS: sh = B^T tile [t][k=0..255] pitch 264 fp16 (pad 8 -> 2-way, free);
//         sx = x_dil fp16 [t][c] pitch 136; sxh aliases sh after phase 1.
//    25.6 KB/block.

typedef _Float16 half8 __attribute__((ext_vector_type(8)));
typedef float floatx4 __attribute__((ext_vector_type(4)));
typedef float float4a __attribute__((ext_vector_type(4), aligned(4)));  // dword-aligned ok

namespace {
constexpr int C  = 128;
constexpr int S_ = 128;
constexpr int T  = 8192;
constexpr int B_ = 2;
constexpr int L_ = 20;
constexpr int NT = 32;        // time tile per block
constexpr int NTH = 512;      // threads per block (8 waves)
constexpr int P1 = 264;       // 256 + 8 fp16 pad
constexpr int P2 = 136;       // 128 + 8 fp16 pad
constexpr int DIL[L_] = {1,2,4,8,16,32,64,128,256,512,
                         1,2,4,8,16,32,64,128,256,512};
// preconverted weight geometry (units: half8 fragments)
constexpr int WD_FRAG_L = 8 * 4 * 128;        // 4096 frags per layer (w_dil)
constexpr int W1_FRAG_L = 4 * 4 * 128;        // 2048 frags per layer (wt/wsg/wk)
constexpr int NWD = L_ * WD_FRAG_L;           // 81920
constexpr int NW1 = L_ * W1_FRAG_L;           // 40960
}

__device__ __forceinline__ float fast_tanh(float x) { return 1.0f - 2.0f / (__expf(2.0f * x) + 1.0f); }
__device__ __forceinline__ float fast_sig (float x) { return 1.0f / (1.0f + __expf(-x)); }

// Convert fp32 weights -> fp16 fragments, layout [layer][kc][q][row][j=8].
//  wd frag (kc 0..7): tap = kc>>2, ci = (kc&3)*32 + q*8 + j, src wd[l][row][ci][tap]
//  w1 frag (kc 0..3): cin = kc*32 + q*8 + j,                src w [l][row][cin]
__global__ __launch_bounds__(256) void prep_w(
    const float* __restrict__ wd, const float* __restrict__ wt,
    const float* __restrict__ wsg, const float* __restrict__ wk,
    _Float16* __restrict__ out)   // [wd16 | wt16 | wsg16 | wk16]
{
    int fi = blockIdx.x * 256 + threadIdx.x;
    if (fi < NWD) {
        int i  = fi / WD_FRAG_L;
        int r  = fi % WD_FRAG_L;
        int kc = r >> 9;
        int q  = (r >> 7) & 3;
        int row = r & 127;
        int tap = kc >> 2;
        int ci0 = (kc & 3) * 32 + q * 8;
        const float* s = wd + ((size_t)(i * 128 + row) * 128 + ci0) * 2 + tap;
        half8 v;
#pragma unroll
        for (int j = 0; j < 8; ++j) v[j] = (_Float16)s[2 * j];
        *(half8*)(out + (size_t)fi * 8) = v;
        return;
    }
    int fi2 = fi - NWD;
    if (fi2 >= 3 * NW1) return;
    int mtx = fi2 / NW1;                 // 0=wt, 1=wsg, 2=wk
    int r   = fi2 % NW1;
    int i   = r / W1_FRAG_L;
    int rr  = r % W1_FRAG_L;
    int kc  = rr >> 9;
    int q   = (rr >> 7) & 3;
    int row = rr & 127;
    const float* base = (mtx == 0) ? wt : ((mtx == 1) ? wsg : wk);
    const float* s = base + (size_t)(i * 128 + row) * 128 + kc * 32 + q * 8;
    half8 v;
#pragma unroll
    for (int j = 0; j < 8; ++j) v[j] = (_Float16)s[j];
    *(half8*)(out + (size_t)(NWD + fi2) * 8) = v;
}

__global__ __launch_bounds__(256) void in_conv(
    const float* __restrict__ x, const float* __restrict__ w_in,
    const float* __restrict__ b_in, float* __restrict__ h0)
{
    int idx = blockIdx.x * 256 + threadIdx.x;   // over B*C*T = 2^21
    int t = idx & (T - 1);
    int c = (idx >> 13) & (C - 1);
    int b = idx >> 20;
    h0[idx] = w_in[c] * x[b * T + t] + b_in[c];
}

__global__ __launch_bounds__(NTH, 4) void layer_k(
    const float* __restrict__ h_in,   // [B,C,T]
    float* __restrict__ h_out,        // [B,C,T] or nullptr (last layer)
    float* __restrict__ skip_out,     // [B,S,T]
    const _Float16* __restrict__ wd16, const float* __restrict__ bd,
    const _Float16* __restrict__ wt16, const float* __restrict__ bt,
    const _Float16* __restrict__ ws16, const float* __restrict__ bs,
    const _Float16* __restrict__ wk16, const float* __restrict__ bk,
    int d)
{
    __shared__ _Float16 sh[NT * P1];   // [t][k]: k<128 = h[t-d][ci], k>=128 = h[t][ci]
    __shared__ _Float16 sx[NT * P2];   // x_dil fp16, [t][c]
    _Float16* sxh = sh;                // x_h fp16, [t][c] — reuses sh after phase 1

    const int tid = threadIdx.x;
    const int b   = blockIdx.y;
    const int t0  = blockIdx.x * NT;
    const float* hb = h_in + (size_t)b * C * T;

    // ---- stage h tiles (global [c][t] -> LDS [t][k], fp16) ----
    for (int f = tid; f < C * (NT / 4); f += NTH) {      // current tap -> cols 128+ci
        int ci = f >> 3, tq = f & 7;
        float4 v = *(const float4*)&hb[ci * T + t0 + tq * 4];
        _Float16* p = &sh[(tq * 4) * P1 + 128 + ci];
        p[0] = (_Float16)v.x; p[P1] = (_Float16)v.y;
        p[2 * P1] = (_Float16)v.z; p[3 * P1] = (_Float16)v.w;
    }
    for (int f = tid; f < C * (NT / 4); f += NTH) {      // dilated tap (any d)
        int ci = f >> 3, tq = f & 7;
        int ts = t0 + tq * 4 - d;
        float4 v;
        if (ts >= 0) {
            float4a u = *(const float4a*)&hb[ci * T + ts];   // dword-aligned load
            v = make_float4(u.x, u.y, u.z, u.w);
        } else {                                              // only first blocks
            v.x = 0.f;
            v.y = (ts + 1 >= 0) ? hb[ci * T + ts + 1] : 0.f;
            v.z = (ts + 2 >= 0) ? hb[ci * T + ts + 2] : 0.f;
            v.w = (ts + 3 >= 0) ? hb[ci * T + ts + 3] : 0.f;
        }
        _Float16* p = &sh[(tq * 4) * P1 + ci];
        p[0] = (_Float16)v.x; p[P1] = (_Float16)v.y;
        p[2 * P1] = (_Float16)v.z; p[3 * P1] = (_Float16)v.w;
    }
    __syncthreads();

    const int lane = tid & 63;
    const int wv   = tid >> 6;      // 0..7: c_out slice
    const int m16  = lane & 15;     // m (A row) / n (B col) / D col
    const int q    = lane >> 4;     // 0..3
    const int cb   = wv * 16;       // wave's c_out base: ONE m-tile

    // ===== phase 1: x_dil, K=256 =====
    half8 wdf[8];
#pragma unroll
    for (int kc = 0; kc < 8; ++kc)
        wdf[kc] = *(const half8*)(wd16 + (size_t)((kc * 4 + q) * 128 + cb + m16) * 8);
    floatx4 bias_d;
#pragma unroll
    for (int r = 0; r < 4; ++r) bias_d[r] = bd[cb + q * 4 + r];

    floatx4 xdacc[2];
#pragma unroll
    for (int nt = 0; nt < 2; ++nt) {
        const int rt = nt * 16 + m16;               // time-row within tile
        const _Float16* br = &sh[rt * P1 + q * 8];
        half8 bf[8];
#pragma unroll
        for (int kc = 0; kc < 8; ++kc) bf[kc] = *(const half8*)(br + kc * 32);
        floatx4 acc = bias_d;
#pragma unroll
        for (int kc = 0; kc < 8; ++kc)
            acc = __builtin_amdgcn_mfma_f32_16x16x32_f16(wdf[kc], bf[kc], acc, 0, 0, 0);
        xdacc[nt] = acc;
        _Float16* px = &sx[rt * P2 + cb + q * 4];
#pragma unroll
        for (int r = 0; r < 4; ++r) px[r] = (_Float16)acc[r];
    }
    __syncthreads();   // sx ready; sh free for reuse as sxh

    // ===== phase 2: tanh/sig convs + gate + residual, K=128 =====
    half8 wtf[4], wsf[4];
#pragma unroll
    for (int kc = 0; kc < 4; ++kc) {
        const size_t off = (size_t)((kc * 4 + q) * 128 + cb + m16) * 8;
        wtf[kc] = *(const half8*)(wt16 + off);
        wsf[kc] = *(const half8*)(ws16 + off);
    }
    floatx4 bias_t, bias_s;
#pragma unroll
    for (int r = 0; r < 4; ++r) {
        bias_t[r] = bt[cb + q * 4 + r];
        bias_s[r] = bs[cb + q * 4 + r];
    }

    float* ho = h_out ? h_out + (size_t)b * C * T : nullptr;
#pragma unroll
    for (int nt = 0; nt < 2; ++nt) {
        const int rt = nt * 16 + m16;
        const _Float16* br = &sx[rt * P2 + q * 8];
        half8 bf[4];
#pragma unroll
        for (int kc = 0; kc < 4; ++kc) bf[kc] = *(const half8*)(br + kc * 32);
        floatx4 at = bias_t, as = bias_s;
#pragma unroll
        for (int kc = 0; kc < 4; ++kc) {
            at = __builtin_amdgcn_mfma_f32_16x16x32_f16(wtf[kc], bf[kc], at, 0, 0, 0);
            as = __builtin_amdgcn_mfma_f32_16x16x32_f16(wsf[kc], bf[kc], as, 0, 0, 0);
        }
        _Float16* pxh = &sxh[rt * P2 + cb + q * 4];
#pragma unroll
        for (int r = 0; r < 4; ++r) {
            float xh = fast_tanh(at[r]) * fast_sig(as[r]);
            pxh[r] = (_Float16)xh;
            if (ho)
                ho[(size_t)(cb + q * 4 + r) * T + t0 + rt] = xh + xdacc[nt][r];
        }
    }
    __syncthreads();   // sxh ready

    // ===== phase 3: skip conv, K=128 =====
    half8 wkf[4];
#pragma unroll
    for (int kc = 0; kc < 4; ++kc)
        wkf[kc] = *(const half8*)(wk16 + (size_t)((kc * 4 + q) * 128 + cb + m16) * 8);
    floatx4 bias_k;
#pragma unroll
    for (int r = 0; r < 4; ++r) bias_k[r] = bk[cb + q * 4 + r];

    float* so = skip_out + (size_t)b * S_ * T;
#pragma unroll
    for (int nt = 0; nt < 2; ++nt) {
        const int rt = nt * 16 + m16;
        const _Float16* br = &sxh[rt * P2 + q * 8];
        half8 bf[4];
#pragma unroll
        for (int kc = 0; kc < 4; ++kc) bf[kc] = *(const half8*)(br + kc * 32);
        floatx4 ak = bias_k;
#pragma unroll
        for (int kc = 0; kc < 4; ++kc)
            ak = __builtin_amdgcn_mfma_f32_16x16x32_f16(wkf[kc], bf[kc], ak, 0, 0, 0);
#pragma unroll
        for (int r = 0; r < 4; ++r)
            so[(size_t)(cb + q * 4 + r) * T + t0 + rt] = ak[r];
    }
}

extern "C" void kernel_launch(void* const* d_in, const int* in_sizes, int n_in,
                              void* d_out, int out_size, void* d_ws, size_t ws_size,
                              hipStream_t stream)
{
    const float* x      = (const float*)d_in[0];
    const float* w_in   = (const float*)d_in[1];
    const float* b_in   = (const float*)d_in[2];
    const float* w_dil  = (const float*)d_in[3];
    const float* b_dil  = (const float*)d_in[4];
    const float* w_tanh = (const float*)d_in[5];
    const float* b_tanh = (const float*)d_in[6];
    const float* w_sig  = (const float*)d_in[7];
    const float* b_sig  = (const float*)d_in[8];
    const float* w_skip = (const float*)d_in[9];
    const float* b_skip = (const float*)d_in[10];

    float* outs  = (float*)d_out;                        // [L,B,C,T]
    float* skips = outs + (size_t)L_ * B_ * C * T;       // [L,B,S,T]

    // d_ws: preconverted fp16 weights, 3.28 MB total
    _Float16* w16   = (_Float16*)d_ws;
    _Float16* wd16  = w16;                                       // [L][4096]*8
    _Float16* wt16  = w16 + (size_t)NWD * 8;                     // [L][2048]*8
    _Float16* wsg16 = wt16 + (size_t)NW1 * 8;
    _Float16* wk16  = wsg16 + (size_t)NW1 * 8;

    const int total_frags = NWD + 3 * NW1;                       // 204800
    prep_w<<<dim3((total_frags + 255) / 256), dim3(256), 0, stream>>>(
        w_dil, w_tanh, w_sig, w_skip, w16);

    in_conv<<<dim3(B_ * C * T / 256), dim3(256), 0, stream>>>(x, w_in, b_in, outs);

    for (int i = 0; i < L_; ++i) {
        const float* h_in  = outs + (size_t)i * B_ * C * T;
        float* h_out = (i + 1 < L_) ? outs + (size_t)(i + 1) * B_ * C * T : nullptr;
        float* sk_o  = skips + (size_t)i * B_ * S_ * T;
        layer_k<<<dim3(T / NT, B_), dim3(NTH), 0, stream>>>(
            h_in, h_out, sk_o,
            wd16  + (size_t)i * WD_FRAG_L * 8, b_dil  + (size_t)i * C,
            wt16  + (size_t)i * W1_FRAG_L * 8, b_tanh + (size_t)i * C,
            wsg16 + (size_t)i * W1_FRAG_L * 8, b_sig  + (size_t)i * C,
            wk16  + (size_t)i * W1_FRAG_L * 8, b_skip + (size_t)i * C,
            DIL[i]);
    }
}

// Round 5
// 529.211 us; speedup vs baseline: 1.5772x; 1.0253x over previous
//
#include <hip/hip_runtime.h>
#include <math.h>

// WaveNet backbone, fp16-MFMA, v6: fp16 h side-chain in [t][c] layout.
//  v5 post-mortem: TLP ladder flattened (1->2 w/SIMD -10%, 2->4 -5%) =>
//  remaining ~25us/layer is critical-path work, not idleness. Dominant lump:
//  staging re-reads fp32 [B,C,T] h and transposes to LDS with 16 scalar
//  ds_write_b16 + 8 cvt + strided float4 loads per thread, before the first
//  barrier.
//  v6: each layer writes h_next ALSO as fp16 [b][t][c] into a d_ws ping-pong
//  buffer (fp32 [b][c][t] write to d_out unchanged — required output).
//  Staging becomes a contiguous copy: per LDS row, two 256B segments
//  (h16[t][:], h16[t-d][:]) via half8 loads + ds_write_b128. No transpose,
//  no cvt, no unaligned-d special case. Numerically identical to v5 (same
//  single fp32->fp16 rounding, producer-side instead of consumer-side).
//  - Structure: NT=32, 512 thr = 8 waves (wave = one 16-row c_out slice),
//    grid (256,2) = 2 blocks/CU = 4 waves/SIMD, launch_bounds(512,4).
//  - Phases: 1) x_dil = [W0|W1] @ [h16_prv;h16_cur] (K=256 MFMA), fp32 acc.
//            2) tanh/sig convs (K=128), gate; h_next written fp32 [c][t] +
//               fp16 [t][c].
//            3) skip conv (K=128) on x_h.
//  - MFMA 16x16x32 f16 layouts (m89/m91/m120-verified):
//      A[m=lane&15][k=(lane>>4)*8+j], B[k=(lane>>4)*8+j][n=lane&15],
//      D[row=(lane>>4)*4+r][col=lane&15].
//  - LDS: sh [t][k=0..255] pitch 264 (pad 8); sx [t][c] pitch 136;
//    sxh aliases sh. 25.6 KB/block.
//  - d_ws: 3.28MB fp16 weights + 2 x 4.19MB fp16 h ping-pong = 11.7MB.

typedef _Float16 half8 __attribute__((ext_vector_type(8)));
typedef _Float16 half4v __attribute__((ext_vector_type(4)));
typedef float floatx4 __attribute__((ext_vector_type(4)));

namespace {
constexpr int C  = 128;
constexpr int S_ = 128;
constexpr int T  = 8192;
constexpr int B_ = 2;
constexpr int L_ = 20;
constexpr int NT = 32;        // time tile per block
constexpr int NTH = 512;      // threads per block (8 waves)
constexpr int P1 = 264;       // 256 + 8 fp16 pad
constexpr int P2 = 136;       // 128 + 8 fp16 pad
constexpr int DIL[L_] = {1,2,4,8,16,32,64,128,256,512,
                         1,2,4,8,16,32,64,128,256,512};
// preconverted weight geometry (units: half8 fragments)
constexpr int WD_FRAG_L = 8 * 4 * 128;        // 4096 frags per layer (w_dil)
constexpr int W1_FRAG_L = 4 * 4 * 128;        // 2048 frags per layer (wt/wsg/wk)
constexpr int NWD = L_ * WD_FRAG_L;           // 81920
constexpr int NW1 = L_ * W1_FRAG_L;           // 40960
}

__device__ __forceinline__ float fast_tanh(float x) { return 1.0f - 2.0f / (__expf(2.0f * x) + 1.0f); }
__device__ __forceinline__ float fast_sig (float x) { return 1.0f / (1.0f + __expf(-x)); }

// Convert fp32 weights -> fp16 fragments, layout [layer][kc][q][row][j=8].
__global__ __launch_bounds__(256) void prep_w(
    const float* __restrict__ wd, const float* __restrict__ wt,
    const float* __restrict__ wsg, const float* __restrict__ wk,
    _Float16* __restrict__ out)   // [wd16 | wt16 | wsg16 | wk16]
{
    int fi = blockIdx.x * 256 + threadIdx.x;
    if (fi < NWD) {
        int i  = fi / WD_FRAG_L;
        int r  = fi % WD_FRAG_L;
        int kc = r >> 9;
        int q  = (r >> 7) & 3;
        int row = r & 127;
        int tap = kc >> 2;
        int ci0 = (kc & 3) * 32 + q * 8;
        const float* s = wd + ((size_t)(i * 128 + row) * 128 + ci0) * 2 + tap;
        half8 v;
#pragma unroll
        for (int j = 0; j < 8; ++j) v[j] = (_Float16)s[2 * j];
        *(half8*)(out + (size_t)fi * 8) = v;
        return;
    }
    int fi2 = fi - NWD;
    if (fi2 >= 3 * NW1) return;
    int mtx = fi2 / NW1;                 // 0=wt, 1=wsg, 2=wk
    int r   = fi2 % NW1;
    int i   = r / W1_FRAG_L;
    int rr  = r % W1_FRAG_L;
    int kc  = rr >> 9;
    int q   = (rr >> 7) & 3;
    int row = rr & 127;
    const float* base = (mtx == 0) ? wt : ((mtx == 1) ? wsg : wk);
    const float* s = base + (size_t)(i * 128 + row) * 128 + kc * 32 + q * 8;
    half8 v;
#pragma unroll
    for (int j = 0; j < 8; ++j) v[j] = (_Float16)s[j];
    *(half8*)(out + (size_t)(NWD + fi2) * 8) = v;
}

// fp32 h0 -> outs[0], [b][c][t] coalesced
__global__ __launch_bounds__(256) void in_conv(
    const float* __restrict__ x, const float* __restrict__ w_in,
    const float* __restrict__ b_in, float* __restrict__ h0)
{
    int idx = blockIdx.x * 256 + threadIdx.x;   // over B*C*T = 2^21
    int t = idx & (T - 1);
    int c = (idx >> 13) & (C - 1);
    int b = idx >> 20;
    h0[idx] = w_in[c] * x[b * T + t] + b_in[c];
}

// fp16 h0 -> ws, [b][t][c] coalesced (half8 per thread)
__global__ __launch_bounds__(256) void in_conv16(
    const float* __restrict__ x, const float* __restrict__ w_in,
    const float* __restrict__ b_in, _Float16* __restrict__ h16)
{
    int idx = blockIdx.x * 256 + threadIdx.x;   // over B*T*C/8 = 262144
    int c0 = (idx & 15) * 8;
    int t  = (idx >> 4) & (T - 1);
    int b  = idx >> 17;
    float xv = x[b * T + t];
    const float4* wp = (const float4*)(w_in + c0);
    const float4* bp = (const float4*)(b_in + c0);
    float4 w0 = wp[0], w1 = wp[1], b0 = bp[0], b1 = bp[1];
    half8 v;
    v[0] = (_Float16)(w0.x * xv + b0.x); v[1] = (_Float16)(w0.y * xv + b0.y);
    v[2] = (_Float16)(w0.z * xv + b0.z); v[3] = (_Float16)(w0.w * xv + b0.w);
    v[4] = (_Float16)(w1.x * xv + b1.x); v[5] = (_Float16)(w1.y * xv + b1.y);
    v[6] = (_Float16)(w1.z * xv + b1.z); v[7] = (_Float16)(w1.w * xv + b1.w);
    *(half8*)(h16 + (size_t)idx * 8) = v;
}

__global__ __launch_bounds__(NTH, 4) void layer_k(
    const _Float16* __restrict__ hws_in,  // [B,T,C] fp16
    float* __restrict__ h_out,            // [B,C,T] fp32 or nullptr (last)
    _Float16* __restrict__ hws_out,       // [B,T,C] fp16 or nullptr (last)
    float* __restrict__ skip_out,         // [B,S,T]
    const _Float16* __restrict__ wd16, const float* __restrict__ bd,
    const _Float16* __restrict__ wt16, const float* __restrict__ bt,
    const _Float16* __restrict__ ws16, const float* __restrict__ bs,
    const _Float16* __restrict__ wk16, const float* __restrict__ bk,
    int d)
{
    __shared__ __align__(16) _Float16 sh[NT * P1];  // [t][k]: k<128 = h[t-d][ci], k>=128 = h[t][ci]
    __shared__ __align__(16) _Float16 sx[NT * P2];  // x_dil fp16, [t][c]
    _Float16* sxh = sh;                // x_h fp16, [t][c] — reuses sh after phase 1

    const int tid = threadIdx.x;
    const int b   = blockIdx.y;
    const int t0  = blockIdx.x * NT;
    const _Float16* hw = hws_in + (size_t)b * T * C;

    // ---- stage h tiles: contiguous fp16 [t][c] rows -> LDS [t][k], b128 ----
    //  f: chunk(16B)=f&15, tap=(f>>4)&1, tt=f>>5;  1024 chunks = 2/thread
#pragma unroll
    for (int u = 0; u < 2; ++u) {
        int f = tid + u * NTH;
        int chunk = f & 15;
        int tap   = (f >> 4) & 1;
        int tt    = f >> 5;
        int ts    = t0 + tt - (tap ? 0 : d);
        half8 v;
#pragma unroll
        for (int j = 0; j < 8; ++j) v[j] = (_Float16)0.0f;
        if (ts >= 0) v = *(const half8*)(hw + (size_t)ts * C + chunk * 8);
        *(half8*)(&sh[tt * P1 + tap * 128 + chunk * 8]) = v;
    }
    __syncthreads();

    const int lane = tid & 63;
    const int wv   = tid >> 6;      // 0..7: c_out slice
    const int m16  = lane & 15;     // m (A row) / n (B col) / D col
    const int q    = lane >> 4;     // 0..3
    const int cb   = wv * 16;       // wave's c_out base: ONE m-tile

    // ===== phase 1: x_dil, K=256 =====
    half8 wdf[8];
#pragma unroll
    for (int kc = 0; kc < 8; ++kc)
        wdf[kc] = *(const half8*)(wd16 + (size_t)((kc * 4 + q) * 128 + cb + m16) * 8);
    floatx4 bias_d;
#pragma unroll
    for (int r = 0; r < 4; ++r) bias_d[r] = bd[cb + q * 4 + r];

    floatx4 xdacc[2];
#pragma unroll
    for (int nt = 0; nt < 2; ++nt) {
        const int rt = nt * 16 + m16;               // time-row within tile
        const _Float16* br = &sh[rt * P1 + q * 8];
        half8 bf[8];
#pragma unroll
        for (int kc = 0; kc < 8; ++kc) bf[kc] = *(const half8*)(br + kc * 32);
        floatx4 acc = bias_d;
#pragma unroll
        for (int kc = 0; kc < 8; ++kc)
            acc = __builtin_amdgcn_mfma_f32_16x16x32_f16(wdf[kc], bf[kc], acc, 0, 0, 0);
        xdacc[nt] = acc;
        _Float16* px = &sx[rt * P2 + cb + q * 4];
#pragma unroll
        for (int r = 0; r < 4; ++r) px[r] = (_Float16)acc[r];
    }
    __syncthreads();   // sx ready; sh free for reuse as sxh

    // ===== phase 2: tanh/sig convs + gate + residual, K=128 =====
    half8 wtf[4], wsf[4];
#pragma unroll
    for (int kc = 0; kc < 4; ++kc) {
        const size_t off = (size_t)((kc * 4 + q) * 128 + cb + m16) * 8;
        wtf[kc] = *(const half8*)(wt16 + off);
        wsf[kc] = *(const half8*)(ws16 + off);
    }
    floatx4 bias_t, bias_s;
#pragma unroll
    for (int r = 0; r < 4; ++r) {
        bias_t[r] = bt[cb + q * 4 + r];
        bias_s[r] = bs[cb + q * 4 + r];
    }

    float*     ho  = h_out   ? h_out   + (size_t)b * C * T : nullptr;
    _Float16*  hwo = hws_out ? hws_out + (size_t)b * T * C : nullptr;
#pragma unroll
    for (int nt = 0; nt < 2; ++nt) {
        const int rt = nt * 16 + m16;
        const _Float16* br = &sx[rt * P2 + q * 8];
        half8 bf[4];
#pragma unroll
        for (int kc = 0; kc < 4; ++kc) bf[kc] = *(const half8*)(br + kc * 32);
        floatx4 at = bias_t, as = bias_s;
#pragma unroll
        for (int kc = 0; kc < 4; ++kc) {
            at = __builtin_amdgcn_mfma_f32_16x16x32_f16(wtf[kc], bf[kc], at, 0, 0, 0);
            as = __builtin_amdgcn_mfma_f32_16x16x32_f16(wsf[kc], bf[kc], as, 0, 0, 0);
        }
        _Float16* pxh = &sxh[rt * P2 + cb + q * 4];
        half4v hv;
#pragma unroll
        for (int r = 0; r < 4; ++r) {
            float xh = fast_tanh(at[r]) * fast_sig(as[r]);
            pxh[r] = (_Float16)xh;
            float hn = xh + xdacc[nt][r];
            hv[r] = (_Float16)hn;
            if (ho)
                ho[(size_t)(cb + q * 4 + r) * T + t0 + rt] = hn;
        }
        if (hwo)
            *(half4v*)(hwo + (size_t)(t0 + rt) * C + cb + q * 4) = hv;
    }
    __syncthreads();   // sxh ready

    // ===== phase 3: skip conv, K=128 =====
    half8 wkf[4];
#pragma unroll
    for (int kc = 0; kc < 4; ++kc)
        wkf[kc] = *(const half8*)(wk16 + (size_t)((kc * 4 + q) * 128 + cb + m16) * 8);
    floatx4 bias_k;
#pragma unroll
    for (int r = 0; r < 4; ++r) bias_k[r] = bk[cb + q * 4 + r];

    float* so = skip_out + (size_t)b * S_ * T;
#pragma unroll
    for (int nt = 0; nt < 2; ++nt) {
        const int rt = nt * 16 + m16;
        const _Float16* br = &sxh[rt * P2 + q * 8];
        half8 bf[4];
#pragma unroll
        for (int kc = 0; kc < 4; ++kc) bf[kc] = *(const half8*)(br + kc * 32);
        floatx4 ak = bias_k;
#pragma unroll
        for (int kc = 0; kc < 4; ++kc)
            ak = __builtin_amdgcn_mfma_f32_16x16x32_f16(wkf[kc], bf[kc], ak, 0, 0, 0);
#pragma unroll
        for (int r = 0; r < 4; ++r)
            so[(size_t)(cb + q * 4 + r) * T + t0 + rt] = ak[r];
    }
}

extern "C" void kernel_launch(void* const* d_in, const int* in_sizes, int n_in,
                              void* d_out, int out_size, void* d_ws, size_t ws_size,
                              hipStream_t stream)
{
    const float* x      = (const float*)d_in[0];
    const float* w_in   = (const float*)d_in[1];
    const float* b_in   = (const float*)d_in[2];
    const float* w_dil  = (const float*)d_in[3];
    const float* b_dil  = (const float*)d_in[4];
    const float* w_tanh = (const float*)d_in[5];
    const float* b_tanh = (const float*)d_in[6];
    const float* w_sig  = (const float*)d_in[7];
    const float* b_sig  = (const float*)d_in[8];
    const float* w_skip = (const float*)d_in[9];
    const float* b_skip = (const float*)d_in[10];

    float* outs  = (float*)d_out;                        // [L,B,C,T]
    float* skips = outs + (size_t)L_ * B_ * C * T;       // [L,B,S,T]

    // d_ws: 3.28MB fp16 weights + 2x fp16 h ping-pong (4.19MB each)
    _Float16* w16   = (_Float16*)d_ws;
    _Float16* wd16  = w16;                                       // [L][4096]*8
    _Float16* wt16  = w16 + (size_t)NWD * 8;                     // [L][2048]*8
    _Float16* wsg16 = wt16 + (size_t)NW1 * 8;
    _Float16* wk16  = wsg16 + (size_t)NW1 * 8;
    _Float16* h16a  = wk16 + (size_t)NW1 * 8;                    // [B,T,C] fp16
    _Float16* h16b  = h16a + (size_t)B_ * T * C;

    const int total_frags = NWD + 3 * NW1;                       // 204800
    prep_w<<<dim3((total_frags + 255) / 256), dim3(256), 0, stream>>>(
        w_dil, w_tanh, w_sig, w_skip, w16);

    in_conv<<<dim3(B_ * C * T / 256), dim3(256), 0, stream>>>(x, w_in, b_in, outs);
    in_conv16<<<dim3(B_ * T * C / 8 / 256), dim3(256), 0, stream>>>(x, w_in, b_in, h16a);

    for (int i = 0; i < L_; ++i) {
        const _Float16* hw_in = (i & 1) ? h16b : h16a;
        _Float16* hw_out = (i + 1 < L_) ? ((i & 1) ? h16a : h16b) : nullptr;
        float* h_out = (i + 1 < L_) ? outs + (size_t)(i + 1) * B_ * C * T : nullptr;
        float* sk_o  = skips + (size_t)i * B_ * S_ * T;
        layer_k<<<dim3(T / NT, B_), dim3(NTH), 0, stream>>>(
            hw_in, h_out, hw_out, sk_o,
            wd16  + (size_t)i * WD_FRAG_L * 8, b_dil  + (size_t)i * C,
            wt16  + (size_t)i * W1_FRAG_L * 8, b_tanh + (size_t)i * C,
            wsg16 + (size_t)i * W1_FRAG_L * 8, b_sig  + (size_t)i * C,
            wk16  + (size_t)i * W1_FRAG_L * 8, b_skip + (size_t)i * C,
            DIL[i]);
    }
}